// Round 6
// baseline (130.922 us; speedup 1.0000x reference)
//
#include <hip/hip_runtime.h>

#define AS1 __attribute__((address_space(1)))
#define AS3 __attribute__((address_space(3)))

constexpr int BATCH = 131072;
constexpr int FEAT  = 384;
constexpr int F4    = FEAT / 4;            // 96 float4 per row
constexpr float ALPHA = 0.2f;
constexpr int BLOCK   = 256;               // 4 waves
constexpr int NBLOCKS = 512;               // 2 blocks/CU co-resident
constexpr int ROWS_PER_TILE = 8;           // 2 rows per wave
constexpr int TILE_F4 = ROWS_PER_TILE * F4;       // 768 float4 = 12 KB/array
constexpr int NTILES  = BATCH / ROWS_PER_TILE;    // 16384
constexpr int TILES_PER_BLOCK = NTILES / NBLOCKS; // 32, exact

__device__ __forceinline__ float wdot(const float4& w, const float4& a,
                                      const float4& p, const float4& n) {
    float dp, dn, r;
    dp = a.x - p.x; dn = a.x - n.x; r  = w.x * (dp * dp - dn * dn);
    dp = a.y - p.y; dn = a.y - n.y; r += w.y * (dp * dp - dn * dn);
    dp = a.z - p.z; dn = a.z - n.z; r += w.z * (dp * dp - dn * dn);
    dp = a.w - p.w; dn = a.w - n.w; r += w.w * (dp * dp - dn * dn);
    return r;
}

// WAVE-PRIVATE staging: wave w stages exactly its own 2-row slice
// (tile-float4 [192w, 192w+192)) of A/P/N. No inter-wave dependency ->
// no barriers in the stream loop; each wave free-runs on its own vmcnt
// pipeline. (R5 evidence: barriers vs none is identical — we sit at the
// aggregate memory-system BW ceiling, ~6 TB/s delivered.)
__device__ __forceinline__ void issue_tile(int wbase, int lane,
    const float4* __restrict__ gA, const float4* __restrict__ gP,
    const float4* __restrict__ gN,
    float4* bA, float4* bP, float4* bN)
{
    #pragma unroll
    for (int j = 0; j < 3; ++j) {
        const int off = wbase + 64 * j;
        __builtin_amdgcn_global_load_lds((const AS1 void*)(gA + off + lane),
                                         (AS3 void*)(bA + off), 16, 0, 0);
        __builtin_amdgcn_global_load_lds((const AS1 void*)(gP + off + lane),
                                         (AS3 void*)(bP + off), 16, 0, 0);
        __builtin_amdgcn_global_load_lds((const AS1 void*)(gN + off + lane),
                                         (AS3 void*)(bN + off), 16, 0, 0);
    }
}

__global__ __launch_bounds__(BLOCK) void triplet_fused(
    const float4* __restrict__ A, const float4* __restrict__ P,
    const float4* __restrict__ N, const float* __restrict__ W,
    float* __restrict__ partial, unsigned int* __restrict__ cnt,
    float* __restrict__ out)
{
    __shared__ float4 sA[2][TILE_F4];
    __shared__ float4 sP[2][TILE_F4];
    __shared__ float4 sN[2][TILE_F4];
    __shared__ float wpart[BLOCK / 64];
    __shared__ int isLast;
    __shared__ float red[BLOCK];

    const int lane  = threadIdx.x & 63;
    const int wave  = threadIdx.x >> 6;
    const int bid   = blockIdx.x;
    const int wbase = 192 * wave;            // this wave's slice in the tile

    const float4* W4 = reinterpret_cast<const float4*>(W);
    float4 w0 = W4[lane];
    float4 w1 = W4[(lane < 32) ? (64 + lane) : (lane - 32)];
    float4 w2 = W4[32 + lane];
    w0.x = expf(w0.x); w0.y = expf(w0.y); w0.z = expf(w0.z); w0.w = expf(w0.w);
    w1.x = expf(w1.x); w1.y = expf(w1.y); w1.z = expf(w1.z); w1.w = expf(w1.w);
    w2.x = expf(w2.x); w2.y = expf(w2.y); w2.z = expf(w2.z); w2.w = expf(w2.w);
    const bool lo = (lane < 32);

    float acc = 0.f;

    issue_tile(wbase, lane, A + (size_t)bid * TILE_F4, P + (size_t)bid * TILE_F4,
               N + (size_t)bid * TILE_F4, sA[0], sP[0], sN[0]);

    for (int i = 0; i < TILES_PER_BLOCK; ++i) {
        if (i + 1 < TILES_PER_BLOCK) {
            const size_t g = (size_t)(bid + NBLOCKS * (i + 1)) * TILE_F4;
            issue_tile(wbase, lane, A + g, P + g, N + g,
                       sA[(i + 1) & 1], sP[(i + 1) & 1], sN[(i + 1) & 1]);
            asm volatile("s_waitcnt vmcnt(9)" ::: "memory");
        } else {
            asm volatile("s_waitcnt vmcnt(0)" ::: "memory");
        }
        __builtin_amdgcn_sched_barrier(0);

        const int b = i & 1;
        const float4 a0 = sA[b][wbase + lane];
        const float4 p0 = sP[b][wbase + lane];
        const float4 n0 = sN[b][wbase + lane];
        const float4 a1 = sA[b][wbase + 64 + lane];
        const float4 p1 = sP[b][wbase + 64 + lane];
        const float4 n1 = sN[b][wbase + 64 + lane];
        const float4 a2 = sA[b][wbase + 128 + lane];
        const float4 p2 = sP[b][wbase + 128 + lane];
        const float4 n2 = sN[b][wbase + 128 + lane];

        const float v0 = wdot(w0, a0, p0, n0);
        const float v1 = wdot(w1, a1, p1, n1);
        const float v2 = wdot(w2, a2, p2, n2);

        float x0 = v0 + (lo ? v1 : 0.f);
        float x1 = v2 + (lo ? 0.f : v1);
        #pragma unroll
        for (int m = 1; m < 64; m <<= 1) {
            x0 += __shfl_xor(x0, m, 64);
            x1 += __shfl_xor(x1, m, 64);
        }
        acc += fmaxf(x0 + ALPHA, 0.f) + fmaxf(x1 + ALPHA, 0.f);
    }

    if (lane == 0) wpart[wave] = acc;
    __syncthreads();
    if (threadIdx.x == 0) {
        partial[bid] = wpart[0] + wpart[1] + wpart[2] + wpart[3];
        __threadfence();                              // publish partial (device scope)
        unsigned int old = atomicAdd(cnt, 1u);        // device-scope by default
        isLast = (old == NBLOCKS - 1) ? 1 : 0;
    }
    __syncthreads();

    if (isLast) {
        __threadfence();                              // acquire all partials
        float s = 0.f;
        for (int i = threadIdx.x; i < NBLOCKS; i += BLOCK) s += partial[i];
        red[threadIdx.x] = s;
        __syncthreads();
        #pragma unroll
        for (int ofs = BLOCK / 2; ofs > 0; ofs >>= 1) {
            if (threadIdx.x < ofs) red[threadIdx.x] += red[threadIdx.x + ofs];
            __syncthreads();
        }
        if (threadIdx.x == 0) out[0] = red[0] / (float)BATCH;
    }
}

extern "C" void kernel_launch(void* const* d_in, const int* in_sizes, int n_in,
                              void* d_out, int out_size, void* d_ws, size_t ws_size,
                              hipStream_t stream) {
    const float4* A = (const float4*)d_in[0];
    const float4* P = (const float4*)d_in[1];
    const float4* N = (const float4*)d_in[2];
    const float*  W = (const float*)d_in[3];
    float* partial = (float*)d_ws;                    // NBLOCKS floats
    unsigned int* cnt = (unsigned int*)((char*)d_ws + NBLOCKS * sizeof(float));
    float* out = (float*)d_out;

    // reset completion counter each call (graph-capturable memset node)
    hipMemsetAsync(cnt, 0, sizeof(unsigned int), stream);
    triplet_fused<<<NBLOCKS, BLOCK, 0, stream>>>(A, P, N, W, partial, cnt, out);
}

// Round 7
// 105.438 us; speedup vs baseline: 1.2417x; 1.2417x over previous
//
#include <hip/hip_runtime.h>

#define AS1 __attribute__((address_space(1)))
#define AS3 __attribute__((address_space(3)))

constexpr int BATCH = 131072;
constexpr int FEAT  = 384;
constexpr int F4    = FEAT / 4;            // 96 float4 per row
constexpr float ALPHA = 0.2f;
constexpr int BLOCK   = 256;               // 4 waves
constexpr int NBLOCKS = 512;               // 2 blocks/CU co-resident
constexpr int ROWS_PER_TILE = 8;           // 2 rows per wave
constexpr int TILE_F4 = ROWS_PER_TILE * F4;       // 768 float4 = 12 KB/array
constexpr int NTILES  = BATCH / ROWS_PER_TILE;    // 16384
constexpr int TILES_PER_BLOCK = NTILES / NBLOCKS; // 32, exact

__device__ __forceinline__ float wdot(const float4& w, const float4& a,
                                      const float4& p, const float4& n) {
    float dp, dn, r;
    dp = a.x - p.x; dn = a.x - n.x; r  = w.x * (dp * dp - dn * dn);
    dp = a.y - p.y; dn = a.y - n.y; r += w.y * (dp * dp - dn * dn);
    dp = a.z - p.z; dn = a.z - n.z; r += w.z * (dp * dp - dn * dn);
    dp = a.w - p.w; dn = a.w - n.w; r += w.w * (dp * dp - dn * dn);
    return r;
}

// WAVE-PRIVATE staging: wave w stages exactly its own 2-row slice
// (tile-float4 [192w, 192w+192)) of A/P/N. No inter-wave dependency ->
// no barriers in the stream loop; each wave free-runs on its own vmcnt
// pipeline. R5/R6 evidence: this sits at the aggregate memory-system
// BW ceiling (~6 TB/s delivered); fusing the finish kernel regresses
// (device-scope fences perturb the streaming loop).
__device__ __forceinline__ void issue_tile(int wbase, int lane,
    const float4* __restrict__ gA, const float4* __restrict__ gP,
    const float4* __restrict__ gN,
    float4* bA, float4* bP, float4* bN)
{
    #pragma unroll
    for (int j = 0; j < 3; ++j) {
        const int off = wbase + 64 * j;
        __builtin_amdgcn_global_load_lds((const AS1 void*)(gA + off + lane),
                                         (AS3 void*)(bA + off), 16, 0, 0);
        __builtin_amdgcn_global_load_lds((const AS1 void*)(gP + off + lane),
                                         (AS3 void*)(bP + off), 16, 0, 0);
        __builtin_amdgcn_global_load_lds((const AS1 void*)(gN + off + lane),
                                         (AS3 void*)(bN + off), 16, 0, 0);
    }
}

__global__ __launch_bounds__(BLOCK) void triplet_partial(
    const float4* __restrict__ A, const float4* __restrict__ P,
    const float4* __restrict__ N, const float* __restrict__ W,
    float* __restrict__ partial)
{
    __shared__ float4 sA[2][TILE_F4];
    __shared__ float4 sP[2][TILE_F4];
    __shared__ float4 sN[2][TILE_F4];
    __shared__ float wpart[BLOCK / 64];

    const int lane  = threadIdx.x & 63;
    const int wave  = threadIdx.x >> 6;
    const int bid   = blockIdx.x;
    const int wbase = 192 * wave;            // this wave's slice in the tile

    // exp(W) fragments; slice starts at an even row so slot s / lane L maps
    // to W4 index (64s + L) mod 96.
    const float4* W4 = reinterpret_cast<const float4*>(W);
    float4 w0 = W4[lane];
    float4 w1 = W4[(lane < 32) ? (64 + lane) : (lane - 32)];
    float4 w2 = W4[32 + lane];
    w0.x = expf(w0.x); w0.y = expf(w0.y); w0.z = expf(w0.z); w0.w = expf(w0.w);
    w1.x = expf(w1.x); w1.y = expf(w1.y); w1.z = expf(w1.z); w1.w = expf(w1.w);
    w2.x = expf(w2.x); w2.y = expf(w2.y); w2.z = expf(w2.z); w2.w = expf(w2.w);
    const bool lo = (lane < 32);

    float acc = 0.f;

    // Block b streams tiles {b, b+512, ...}; each wave pipelines privately.
    issue_tile(wbase, lane, A + (size_t)bid * TILE_F4, P + (size_t)bid * TILE_F4,
               N + (size_t)bid * TILE_F4, sA[0], sP[0], sN[0]);

    for (int i = 0; i < TILES_PER_BLOCK; ++i) {
        if (i + 1 < TILES_PER_BLOCK) {
            const size_t g = (size_t)(bid + NBLOCKS * (i + 1)) * TILE_F4;
            issue_tile(wbase, lane, A + g, P + g, N + g,
                       sA[(i + 1) & 1], sP[(i + 1) & 1], sN[(i + 1) & 1]);
            // wait for THIS wave's tile-i chunks; tile-(i+1)'s 9 stay in flight
            asm volatile("s_waitcnt vmcnt(9)" ::: "memory");
        } else {
            asm volatile("s_waitcnt vmcnt(0)" ::: "memory");
        }
        __builtin_amdgcn_sched_barrier(0);

        const int b = i & 1;
        const float4 a0 = sA[b][wbase + lane];
        const float4 p0 = sP[b][wbase + lane];
        const float4 n0 = sN[b][wbase + lane];
        const float4 a1 = sA[b][wbase + 64 + lane];
        const float4 p1 = sP[b][wbase + 64 + lane];
        const float4 n1 = sN[b][wbase + 64 + lane];
        const float4 a2 = sA[b][wbase + 128 + lane];
        const float4 p2 = sP[b][wbase + 128 + lane];
        const float4 n2 = sN[b][wbase + 128 + lane];

        const float v0 = wdot(w0, a0, p0, n0);
        const float v1 = wdot(w1, a1, p1, n1);
        const float v2 = wdot(w2, a2, p2, n2);

        float x0 = v0 + (lo ? v1 : 0.f);     // row 2*(4*tile + wave)
        float x1 = v2 + (lo ? 0.f : v1);     // row ... + 1
        #pragma unroll
        for (int m = 1; m < 64; m <<= 1) {
            x0 += __shfl_xor(x0, m, 64);
            x1 += __shfl_xor(x1, m, 64);
        }
        acc += fmaxf(x0 + ALPHA, 0.f) + fmaxf(x1 + ALPHA, 0.f);
        // no barrier: buffer (i&1) is re-staged only by THIS wave at i+2,
        // after these ds_reads have completed (their values fed acc above).
    }

    if (lane == 0) wpart[wave] = acc;
    __syncthreads();
    if (threadIdx.x == 0)
        partial[bid] = wpart[0] + wpart[1] + wpart[2] + wpart[3];
}

__global__ __launch_bounds__(256) void triplet_finish(
    const float* __restrict__ partial, float* __restrict__ out)
{
    __shared__ float lds[256];
    float s = 0.f;
    for (int i = threadIdx.x; i < NBLOCKS; i += 256) s += partial[i];
    lds[threadIdx.x] = s;
    __syncthreads();
    for (int ofs = 128; ofs > 0; ofs >>= 1) {
        if (threadIdx.x < ofs) lds[threadIdx.x] += lds[threadIdx.x + ofs];
        __syncthreads();
    }
    if (threadIdx.x == 0) out[0] = lds[0] / (float)BATCH;
}

extern "C" void kernel_launch(void* const* d_in, const int* in_sizes, int n_in,
                              void* d_out, int out_size, void* d_ws, size_t ws_size,
                              hipStream_t stream) {
    const float4* A = (const float4*)d_in[0];
    const float4* P = (const float4*)d_in[1];
    const float4* N = (const float4*)d_in[2];
    const float*  W = (const float*)d_in[3];
    float* partial = (float*)d_ws;   // NBLOCKS floats, fully written each call
    float* out = (float*)d_out;

    triplet_partial<<<NBLOCKS, BLOCK, 0, stream>>>(A, P, N, W, partial);
    triplet_finish<<<1, 256, 0, stream>>>(partial, out);
}